// Round 1
// baseline (2496.262 us; speedup 1.0000x reference)
//
#include <hip/hip_runtime.h>

#define N_NODES 100000
#define N_EDGES 1600000
#define N_FEAT 7
#define HID 128
#define N_CLASS 5
#define N_GRAPHS 8

// ---------------- Layer 1 (in=7) ----------------

__global__ void edge_l1(const float* __restrict__ x, const int* __restrict__ src,
                        const int* __restrict__ dst, const float* __restrict__ ea,
                        const float* __restrict__ We, const float* __restrict__ be,
                        float* __restrict__ agg) {
    int e = blockIdx.x * blockDim.x + threadIdx.x;
    if (e >= N_EDGES) return;
    int s = src[e], d = dst[e];
    float a = ea[e];
#pragma unroll
    for (int k = 0; k < N_FEAT; ++k) {
        float m = x[s * N_FEAT + k] + a * We[k] + be[k];
        m = m > 0.f ? m : 0.f;
        atomicAdd(&agg[d * N_FEAT + k], m);
    }
}

__global__ void node_l1(const float* __restrict__ x, const float* __restrict__ agg,
                        const float* __restrict__ W, const float* __restrict__ b,
                        float* __restrict__ h) {
    __shared__ float t[N_FEAT];
    int n = blockIdx.x;
    int j = threadIdx.x;
    if (j < N_FEAT) t[j] = agg[n * N_FEAT + j] + x[n * N_FEAT + j];
    __syncthreads();
    float acc = b[j];
#pragma unroll
    for (int k = 0; k < N_FEAT; ++k) acc += t[k] * W[k * HID + j];
    h[n * HID + j] = acc > 0.f ? acc : 0.f;
}

// ---------------- Hidden layers (in=128) ----------------

// one edge handled by 128 consecutive threads (k = feature); coalesced
// gather from hin[src] row and coalesced atomic scatter to agg[dst] row.
__global__ void edge_hid(const float* __restrict__ hin, const int* __restrict__ src,
                         const int* __restrict__ dst, const float* __restrict__ ea,
                         const float* __restrict__ We, const float* __restrict__ be,
                         float* __restrict__ agg) {
    long long idx = (long long)blockIdx.x * blockDim.x + threadIdx.x;
    int e = (int)(idx >> 7);
    int k = (int)(idx & 127);
    if (e >= N_EDGES) return;
    int s = src[e], d = dst[e];
    float m = hin[(long long)s * HID + k] + ea[e] * We[k] + be[k];
    m = m > 0.f ? m : 0.f;
    atomicAdd(&agg[(long long)d * HID + k], m);
}

// one block (128 threads) per node: hout[n][j] = relu(sum_k (agg[n][k]+hin[n][k]) * W[k][j] + b[j])
// Safe to call with hout == agg (row n read fully into LDS before write).
__global__ void node_hid(const float* __restrict__ hin, const float* __restrict__ agg,
                         const float* __restrict__ W, const float* __restrict__ b,
                         float* __restrict__ hout) {
    __shared__ float t[HID];
    int n = blockIdx.x;
    int j = threadIdx.x;
    t[j] = agg[(long long)n * HID + j] + hin[(long long)n * HID + j];
    __syncthreads();
    float acc = b[j];
#pragma unroll 8
    for (int k = 0; k < HID; ++k) acc += t[k] * W[k * HID + j];
    hout[(long long)n * HID + j] = acc > 0.f ? acc : 0.f;
}

// ---------------- Pooling + head ----------------

// batch is sorted; run-length accumulate per 64-node chunk, flush per graph-run.
__global__ void pool_kernel(const float* __restrict__ h, const int* __restrict__ batch,
                            float* __restrict__ pool, float* __restrict__ cnt) {
    int n0 = blockIdx.x * 64;
    int j = threadIdx.x;
    int nend = n0 + 64;
    if (nend > N_NODES) nend = N_NODES;
    if (n0 >= N_NODES) return;
    float sum = 0.f;
    int curg = batch[n0];
    int runstart = n0;
    for (int n = n0; n < nend; ++n) {
        int g = batch[n];
        if (g != curg) {
            atomicAdd(&pool[curg * HID + j], sum);
            if (j == 0) atomicAdd(&cnt[curg], (float)(n - runstart));
            sum = 0.f;
            curg = g;
            runstart = n;
        }
        sum += h[(long long)n * HID + j];
    }
    atomicAdd(&pool[curg * HID + j], sum);
    if (j == 0) atomicAdd(&cnt[curg], (float)(nend - runstart));
}

__global__ void final_kernel(const float* __restrict__ pool, const float* __restrict__ cnt,
                             const float* __restrict__ Wlin, const float* __restrict__ blin,
                             float* __restrict__ out) {
    int idx = threadIdx.x;
    if (idx >= N_GRAPHS * N_CLASS) return;
    int g = idx / N_CLASS, c = idx % N_CLASS;
    float invc = 1.f / fmaxf(cnt[g], 1.f);
    float acc = blin[c];
    for (int j = 0; j < HID; ++j) acc += pool[g * HID + j] * invc * Wlin[j * N_CLASS + c];
    out[idx] = acc;
}

extern "C" void kernel_launch(void* const* d_in, const int* in_sizes, int n_in,
                              void* d_out, int out_size, void* d_ws, size_t ws_size,
                              hipStream_t stream) {
    const float* x    = (const float*)d_in[0];
    const int*   ei   = (const int*)d_in[1];
    const float* ea   = (const float*)d_in[2];
    const int*   batch= (const int*)d_in[3];
    const float* We1  = (const float*)d_in[4];
    const float* be1  = (const float*)d_in[5];
    const float* W1   = (const float*)d_in[6];
    const float* b1   = (const float*)d_in[7];
    const float* We2  = (const float*)d_in[8];
    const float* be2  = (const float*)d_in[9];
    const float* W2   = (const float*)d_in[10];
    const float* b2   = (const float*)d_in[11];
    const float* We3  = (const float*)d_in[12];
    const float* be3  = (const float*)d_in[13];
    const float* W3   = (const float*)d_in[14];
    const float* b3   = (const float*)d_in[15];
    const float* Wlin = (const float*)d_in[16];
    const float* blin = (const float*)d_in[17];

    const int* src = ei;
    const int* dst = ei + N_EDGES;

    float* A    = (float*)d_ws;                       // N*HID
    float* B    = A + (size_t)N_NODES * HID;          // N*HID
    float* agg1 = B + (size_t)N_NODES * HID;          // N*N_FEAT
    float* pool = agg1 + (size_t)N_NODES * N_FEAT;    // N_GRAPHS*HID
    float* cnt  = pool + N_GRAPHS * HID;              // N_GRAPHS

    // ---- Layer 1 ----
    hipMemsetAsync(agg1, 0, sizeof(float) * (size_t)N_NODES * N_FEAT, stream);
    edge_l1<<<(N_EDGES + 255) / 256, 256, 0, stream>>>(x, src, dst, ea, We1, be1, agg1);
    node_l1<<<N_NODES, HID, 0, stream>>>(x, agg1, W1, b1, A);   // A = h1

    // ---- Layer 2 ----
    hipMemsetAsync(B, 0, sizeof(float) * (size_t)N_NODES * HID, stream);
    edge_hid<<<(int)(((long long)N_EDGES * HID) / 256), 256, 0, stream>>>(A, src, dst, ea, We2, be2, B);
    node_hid<<<N_NODES, HID, 0, stream>>>(A, B, W2, b2, B);     // B = h2 (in-place)

    // ---- Layer 3 ----
    hipMemsetAsync(A, 0, sizeof(float) * (size_t)N_NODES * HID, stream);
    edge_hid<<<(int)(((long long)N_EDGES * HID) / 256), 256, 0, stream>>>(B, src, dst, ea, We3, be3, A);
    node_hid<<<N_NODES, HID, 0, stream>>>(B, A, W3, b3, A);     // A = h3 (in-place)

    // ---- Pool + head ----
    hipMemsetAsync(pool, 0, sizeof(float) * (N_GRAPHS * HID + N_GRAPHS), stream);
    pool_kernel<<<(N_NODES + 63) / 64, HID, 0, stream>>>(A, batch, pool, cnt);
    final_kernel<<<1, 64, 0, stream>>>(pool, cnt, Wlin, blin, (float*)d_out);
}

// Round 2
// 942.867 us; speedup vs baseline: 2.6475x; 2.6475x over previous
//
#include <hip/hip_runtime.h>

#define N_NODES 100000
#define N_EDGES 1600000
#define N_FEAT 7
#define HID 128
#define N_CLASS 5
#define N_GRAPHS 8
#define NPB 8   // nodes per block in fused hidden-layer kernel

// ---------------- CSR build (dst-sorted adjacency) ----------------

__global__ void hist_kernel(const int* __restrict__ dst, int* __restrict__ deg) {
    int e = blockIdx.x * blockDim.x + threadIdx.x;
    if (e < N_EDGES) atomicAdd(&deg[dst[e]], 1);
}

// single-block exclusive scan deg -> rowptr (+ copy to cursor)
__global__ __launch_bounds__(1024) void scan_kernel(const int* __restrict__ deg,
                                                    int* __restrict__ rowptr,
                                                    int* __restrict__ cursor) {
    __shared__ int sums[1024];
    const int C = (N_NODES + 1023) / 1024;  // 98
    int tid = threadIdx.x;
    int lo = tid * C;
    int hi = lo + C; if (hi > N_NODES) hi = N_NODES;
    int s = 0;
    for (int i = lo; i < hi; ++i) s += deg[i];
    sums[tid] = s;
    __syncthreads();
    for (int off = 1; off < 1024; off <<= 1) {
        int v = (tid >= off) ? sums[tid - off] : 0;
        __syncthreads();
        sums[tid] += v;
        __syncthreads();
    }
    int run = (tid == 0) ? 0 : sums[tid - 1];
    for (int i = lo; i < hi; ++i) {
        rowptr[i] = run;
        cursor[i] = run;
        run += deg[i];
    }
    if (tid == 1023) rowptr[N_NODES] = sums[1023];
}

// pack (src, edge_attr) into one 8B record at its CSR slot
__global__ void scatter_kernel(const int* __restrict__ src, const int* __restrict__ dst,
                               const float* __restrict__ ea, int* __restrict__ cursor,
                               int2* __restrict__ csr) {
    int e = blockIdx.x * blockDim.x + threadIdx.x;
    if (e >= N_EDGES) return;
    int d = dst[e];
    int p = atomicAdd(&cursor[d], 1);
    csr[p] = make_int2(src[e], __float_as_int(ea[e]));
}

// ---------------- Layer 1 (in=7) ----------------

// one wave per node: strided gather over incoming edges, butterfly reduce
__global__ __launch_bounds__(64) void agg_l1(const float* __restrict__ x,
                                             const int2* __restrict__ csr,
                                             const int* __restrict__ rowptr,
                                             const float* __restrict__ We,
                                             const float* __restrict__ be,
                                             float* __restrict__ agg) {
    int n = blockIdx.x;
    int lane = threadIdx.x;
    int r0 = rowptr[n], r1 = rowptr[n + 1];
    float we[N_FEAT], bee[N_FEAT], p[N_FEAT];
#pragma unroll
    for (int k = 0; k < N_FEAT; ++k) { we[k] = We[k]; bee[k] = be[k]; p[k] = 0.f; }
    for (int i = r0 + lane; i < r1; i += 64) {
        int2 sa = csr[i];
        int s = sa.x;
        float a = __int_as_float(sa.y);
#pragma unroll
        for (int k = 0; k < N_FEAT; ++k) {
            float m = x[s * N_FEAT + k] + a * we[k] + bee[k];
            p[k] += m > 0.f ? m : 0.f;
        }
    }
#pragma unroll
    for (int off = 32; off >= 1; off >>= 1)
#pragma unroll
        for (int k = 0; k < N_FEAT; ++k)
            p[k] += __shfl_xor(p[k], off, 64);
    if (lane == 0) {
#pragma unroll
        for (int k = 0; k < N_FEAT; ++k) agg[n * N_FEAT + k] = p[k];
    }
}

__global__ void node_l1(const float* __restrict__ x, const float* __restrict__ agg,
                        const float* __restrict__ W, const float* __restrict__ b,
                        float* __restrict__ h) {
    __shared__ float t[N_FEAT];
    int n = blockIdx.x;
    int j = threadIdx.x;
    if (j < N_FEAT) t[j] = agg[n * N_FEAT + j] + x[n * N_FEAT + j];
    __syncthreads();
    float acc = b[j];
#pragma unroll
    for (int k = 0; k < N_FEAT; ++k) acc += t[k] * W[k * HID + j];
    h[n * HID + j] = acc > 0.f ? acc : 0.f;
}

// ---------------- Fused hidden layer: gather-aggregate + GEMV ----------------
// block = 128 threads (j = feature), owns NPB consecutive nodes.
// hout MUST differ from hin (other blocks gather hin rows concurrently).
__global__ __launch_bounds__(128) void hidden_layer(
        const float* __restrict__ hin, const int2* __restrict__ csr,
        const int* __restrict__ rowptr, const float* __restrict__ We,
        const float* __restrict__ be, const float* __restrict__ W,
        const float* __restrict__ b, float* __restrict__ hout) {
    __shared__ float t[NPB][HID];
    __shared__ int2 ebuf[128];
    int j = threadIdx.x;
    int n0 = blockIdx.x * NPB;
    float wej = We[j], bej = be[j];

    for (int m = 0; m < NPB; ++m) {
        int n = n0 + m;
        int r0 = rowptr[n], r1 = rowptr[n + 1];
        float acc = 0.f;
        for (int c = r0; c < r1; c += 128) {
            int cnt = r1 - c; if (cnt > 128) cnt = 128;
            __syncthreads();                 // protect ebuf reuse
            if (j < cnt) ebuf[j] = csr[c + j];
            __syncthreads();
            for (int i = 0; i < cnt; ++i) {
                int s = ebuf[i].x;
                float a = __int_as_float(ebuf[i].y);
                float mm = hin[(size_t)s * HID + j] + a * wej + bej;
                acc += mm > 0.f ? mm : 0.f;
            }
        }
        t[m][j] = acc + hin[(size_t)n * HID + j];
    }
    __syncthreads();

    float out[NPB];
#pragma unroll
    for (int m = 0; m < NPB; ++m) out[m] = b[j];
    for (int k = 0; k < HID; ++k) {
        float w = W[k * HID + j];
#pragma unroll
        for (int m = 0; m < NPB; ++m) out[m] += t[m][k] * w;
    }
#pragma unroll
    for (int m = 0; m < NPB; ++m) {
        float v = out[m];
        hout[(size_t)(n0 + m) * HID + j] = v > 0.f ? v : 0.f;
    }
}

// ---------------- Pooling + head ----------------

__global__ void pool_kernel(const float* __restrict__ h, const int* __restrict__ batch,
                            float* __restrict__ pool, float* __restrict__ cnt) {
    int n0 = blockIdx.x * 64;
    int j = threadIdx.x;
    int nend = n0 + 64;
    if (nend > N_NODES) nend = N_NODES;
    if (n0 >= N_NODES) return;
    float sum = 0.f;
    int curg = batch[n0];
    int runstart = n0;
    for (int n = n0; n < nend; ++n) {
        int g = batch[n];
        if (g != curg) {
            atomicAdd(&pool[curg * HID + j], sum);
            if (j == 0) atomicAdd(&cnt[curg], (float)(n - runstart));
            sum = 0.f;
            curg = g;
            runstart = n;
        }
        sum += h[(size_t)n * HID + j];
    }
    atomicAdd(&pool[curg * HID + j], sum);
    if (j == 0) atomicAdd(&cnt[curg], (float)(nend - runstart));
}

__global__ void final_kernel(const float* __restrict__ pool, const float* __restrict__ cnt,
                             const float* __restrict__ Wlin, const float* __restrict__ blin,
                             float* __restrict__ out) {
    int idx = threadIdx.x;
    if (idx >= N_GRAPHS * N_CLASS) return;
    int g = idx / N_CLASS, c = idx % N_CLASS;
    float invc = 1.f / fmaxf(cnt[g], 1.f);
    float acc = blin[c];
    for (int j = 0; j < HID; ++j) acc += pool[g * HID + j] * invc * Wlin[j * N_CLASS + c];
    out[idx] = acc;
}

extern "C" void kernel_launch(void* const* d_in, const int* in_sizes, int n_in,
                              void* d_out, int out_size, void* d_ws, size_t ws_size,
                              hipStream_t stream) {
    const float* x    = (const float*)d_in[0];
    const int*   ei   = (const int*)d_in[1];
    const float* ea   = (const float*)d_in[2];
    const int*   batch= (const int*)d_in[3];
    const float* We1  = (const float*)d_in[4];
    const float* be1  = (const float*)d_in[5];
    const float* W1   = (const float*)d_in[6];
    const float* b1   = (const float*)d_in[7];
    const float* We2  = (const float*)d_in[8];
    const float* be2  = (const float*)d_in[9];
    const float* W2   = (const float*)d_in[10];
    const float* b2   = (const float*)d_in[11];
    const float* We3  = (const float*)d_in[12];
    const float* be3  = (const float*)d_in[13];
    const float* W3   = (const float*)d_in[14];
    const float* b3   = (const float*)d_in[15];
    const float* Wlin = (const float*)d_in[16];
    const float* blin = (const float*)d_in[17];

    const int* src = ei;
    const int* dst = ei + N_EDGES;

    // workspace layout (csr first: 8B-aligned at base)
    char* w = (char*)d_ws;
    int2*  csr    = (int2*)w;                    w += sizeof(int2) * (size_t)N_EDGES;
    float* A      = (float*)w;                   w += sizeof(float) * (size_t)N_NODES * HID;
    float* B      = (float*)w;                   w += sizeof(float) * (size_t)N_NODES * HID;
    float* agg1   = (float*)w;                   w += sizeof(float) * (size_t)N_NODES * N_FEAT;
    float* pool   = (float*)w;                   w += sizeof(float) * N_GRAPHS * HID;
    float* cnt    = (float*)w;                   w += sizeof(float) * N_GRAPHS;
    int*   rowptr = (int*)w;                     w += sizeof(int) * (N_NODES + 1);
    int*   cursor = (int*)w;                     w += sizeof(int) * N_NODES;
    int*   deg    = (int*)w;                     w += sizeof(int) * N_NODES;

    // ---- CSR build ----
    hipMemsetAsync(deg, 0, sizeof(int) * N_NODES, stream);
    hipMemsetAsync(pool, 0, sizeof(float) * (N_GRAPHS * HID + N_GRAPHS), stream);
    hist_kernel<<<(N_EDGES + 255) / 256, 256, 0, stream>>>(dst, deg);
    scan_kernel<<<1, 1024, 0, stream>>>(deg, rowptr, cursor);
    scatter_kernel<<<(N_EDGES + 255) / 256, 256, 0, stream>>>(src, dst, ea, cursor, csr);

    // ---- Layer 1 ----
    agg_l1<<<N_NODES, 64, 0, stream>>>(x, csr, rowptr, We1, be1, agg1);
    node_l1<<<N_NODES, HID, 0, stream>>>(x, agg1, W1, b1, A);            // A = h1

    // ---- Layer 2: A -> B ----
    hidden_layer<<<N_NODES / NPB, 128, 0, stream>>>(A, csr, rowptr, We2, be2, W2, b2, B);

    // ---- Layer 3: B -> A ----
    hidden_layer<<<N_NODES / NPB, 128, 0, stream>>>(B, csr, rowptr, We3, be3, W3, b3, A);

    // ---- Pool + head ----
    pool_kernel<<<(N_NODES + 63) / 64, HID, 0, stream>>>(A, batch, pool, cnt);
    final_kernel<<<1, 64, 0, stream>>>(pool, cnt, Wlin, blin, (float*)d_out);
}